// Round 8
// baseline (19058.098 us; speedup 1.0000x reference)
//
#include <hip/hip_runtime.h>
#include <math.h>

#define NB   256
#define LSEQ 1800
#define NF   50
#define NE   4
#define NH   32
#define G3   96
#define ND   64
#define NHU  32
#define TBLK 8
#define CHUNK 72
#define NCOMP  225   // wave0 compute phases (225*8 = 1800)
#define NPHASE 226   // barrier phases in the main loop

typedef float v2f __attribute__((ext_vector_type(2)));

__device__ __forceinline__ v2f v2fma(v2f a, v2f b, v2f c) {
    return __builtin_elementwise_fma(a, b, c);
}
__device__ __forceinline__ v2f mkv2(float a, float b) { v2f t; t.x = a; t.y = b; return t; }
__device__ __forceinline__ v2f splat2(float s) { v2f t; t.x = s; t.y = s; return t; }

// ---------------------------------------------------------------------------
// Kernel 1: fold input projection into layer-0 input weights.
// Cg[e][f][g] = sum_d Wih0[e][g][d] * W_in[d][f]
// ---------------------------------------------------------------------------
__global__ void compute_C_kernel(const float* __restrict__ Wih0,
                                 const float* __restrict__ W_in,
                                 float* __restrict__ Cg) {
    int e = blockIdx.x;
    for (int idx = threadIdx.x; idx < NF * G3; idx += blockDim.x) {
        int f = idx / G3;
        int g = idx - f * G3;
        const float* wr = Wih0 + ((size_t)e * G3 + g) * ND;
        float s = 0.f;
        #pragma unroll 8
        for (int d = 0; d < ND; d++) s += wr[d] * W_in[d * NF + f];
        Cg[(size_t)e * NF * G3 + idx] = s;
    }
}

__device__ __forceinline__ float fsig(float x) {
    float e = __builtin_amdgcn_exp2f(-1.442695041f * x);
    return __builtin_amdgcn_rcpf(1.f + e);
}
__device__ __forceinline__ float ftanh(float x) {
    x = fmaxf(x, -20.f);
    float e = __builtin_amdgcn_exp2f(-2.885390082f * x);
    return (1.f - e) * __builtin_amdgcn_rcpf(1.f + e);
}

// ---------------------------------------------------------------------------
// 128-thread block (2 waves) per (batch, expert); unrouted blocks exit.
// WAVE SPECIALIZATION with TBLK-step lag:
//   wave0 = layer-0 recurrence. Lane j (halves duplicated) owns gate rows
//     {j,j+32,j+64}, full 32-k dots over h0 (no reduce). After h0(t) it also
//     computes the k-half partials of xg1(t)=Wih1.h0(t) -> xg1 ring.
//   wave1 = layer-1 recurrence (TBLK behind) consuming the xg1 ring, plus
//     the batch duty: x chunk staging and xg0 = (Wih0.W_in).x + d -> xg0 ring.
// Rings are double-buffered per phase; one __syncthreads per phase. Both
// branches execute the same barrier count (wave-uniform divergence).
// h broadcast inside each wave via v_readlane (no DS on the chain).
// ---------------------------------------------------------------------------
__global__ __launch_bounds__(128, 1)
void moe_gru_kernel(const float* __restrict__ x,
                    const int*   __restrict__ horizon,
                    const float* __restrict__ emb,
                    const float* __restrict__ W_gate,
                    const float* __restrict__ b_gate,
                    const float* __restrict__ b_in,
                    const float* __restrict__ Wih0,
                    const float* __restrict__ Whh0,
                    const float* __restrict__ bih0,
                    const float* __restrict__ bhh0,
                    const float* __restrict__ Wih1,
                    const float* __restrict__ Whh1,
                    const float* __restrict__ bih1,
                    const float* __restrict__ bhh1,
                    const float* __restrict__ Wh1,
                    const float* __restrict__ bh1,
                    const float* __restrict__ Wh2,
                    const float* __restrict__ bh2,
                    const float* __restrict__ Cg,
                    float* __restrict__ out) {
    __shared__ __align__(16) float smem[4800 + 3600 + 1536 + 3072];
    float* CT  = smem;            // [f][96] folded xg0 weights (wave1 only)
    float* xs  = smem + 4800;     // [f][CHUNK] transposed x chunk (wave1 only)
    float* rg0 = smem + 8400;     // xg0 ring: [2][TBLK][96]
    float* rg1 = smem + 9936;     // xg1 ring: [2][TBLK][2][96]

    const int bid = blockIdx.x;
    const int b   = bid >> 2;
    const int e   = bid & 3;
    const int tid  = threadIdx.x;
    const int wid  = tid >> 6;
    const int lane = tid & 63;
    const int j    = lane & 31;
    const int hlf  = (lane >> 5) & 1;
    const int hor  = horizon[b];

    // ---- gating (every thread identically, straight from global) ----
    float lg[NE];
    #pragma unroll
    for (int q = 0; q < NE; q++) {
        float s = b_gate[q];
        for (int d = 0; d < ND; d++) s += emb[(size_t)hor * ND + d] * W_gate[q * ND + d];
        lg[q] = s;
    }
    int i1 = 0;
    #pragma unroll
    for (int q = 1; q < NE; q++) if (lg[q] > lg[i1]) i1 = q;
    int i2 = (i1 == 0) ? 1 : 0;
    #pragma unroll
    for (int q = 0; q < NE; q++) if (q != i1 && lg[q] > lg[i2]) i2 = q;
    if (e != i1 && e != i2) return;          // block-uniform
    const float ex2 = expf(lg[i2] - lg[i1]);
    const float wgt = (e == i1) ? (1.f / (1.f + ex2)) : (ex2 / (1.f + ex2));

    const int eG = e * G3;

    if (wid == 0) {
        // =================== wave0: layer-0 recurrence ===================
        v2f w0r[16], w0z[16], w0n[16];          // Whh0 rows, full k
        {
            const float* base = Whh0 + (size_t)eG * NH;
            const float* r0 = base + (size_t)j * NH;
            const float* r1 = base + (size_t)(j + 32) * NH;
            const float* r2 = base + (size_t)(j + 64) * NH;
            #pragma unroll
            for (int q4 = 0; q4 < 8; q4++) {
                float4 qa = ((const float4*)r0)[q4];
                w0r[2*q4] = mkv2(qa.x, qa.y); w0r[2*q4+1] = mkv2(qa.z, qa.w);
                float4 qb = ((const float4*)r1)[q4];
                w0z[2*q4] = mkv2(qb.x, qb.y); w0z[2*q4+1] = mkv2(qb.z, qb.w);
                float4 qc = ((const float4*)r2)[q4];
                w0n[2*q4] = mkv2(qc.x, qc.y); w0n[2*q4+1] = mkv2(qc.z, qc.w);
            }
        }
        v2f u1r[8], u1z[8], u1n[8];             // Wih1 rows, k-half [16*hlf,+16)
        {
            const float* base = Wih1 + (size_t)eG * NH + (hlf << 4);
            const float* r0 = base + (size_t)j * NH;
            const float* r1 = base + (size_t)(j + 32) * NH;
            const float* r2 = base + (size_t)(j + 64) * NH;
            #pragma unroll
            for (int q4 = 0; q4 < 4; q4++) {
                float4 qa = ((const float4*)r0)[q4];
                u1r[2*q4] = mkv2(qa.x, qa.y); u1r[2*q4+1] = mkv2(qa.z, qa.w);
                float4 qb = ((const float4*)r1)[q4];
                u1z[2*q4] = mkv2(qb.x, qb.y); u1z[2*q4+1] = mkv2(qb.z, qb.w);
                float4 qc = ((const float4*)r2)[q4];
                u1n[2*q4] = mkv2(qc.x, qc.y); u1n[2*q4+1] = mkv2(qc.z, qc.w);
            }
        }
        const float b0r = bhh0[eG + j];
        const float b0z = bhh0[eG + j + 32];
        const float b0n = bhh0[eG + j + 64];

        v2f h0v[16];
        #pragma unroll
        for (int k = 0; k < 16; k++) h0v[k] = splat2(0.f);
        float hold0 = 0.f;

        __syncthreads();   // matches wave1 prologue barrier

        for (int p = 0; p < NPHASE; p++) {
            if (p < NCOMP) {
                const float* r0 = rg0 + (p & 1) * (TBLK * 96);
                float* w1 = rg1 + (p & 1) * (TBLK * 192);
                #pragma unroll
                for (int i = 0; i < TBLK; i++) {
                    float xr = r0[i * 96 + j];
                    float xz = r0[i * 96 + 32 + j];
                    float xn = r0[i * 96 + 64 + j];
                    v2f d0 = mkv2(b0r, 0.f), d1 = mkv2(b0z, 0.f), d2 = mkv2(b0n, 0.f);
                    #pragma unroll
                    for (int k = 0; k < 16; k++) {
                        d0 = v2fma(w0r[k], h0v[k], d0);
                        d1 = v2fma(w0z[k], h0v[k], d1);
                        d2 = v2fma(w0n[k], h0v[k], d2);
                    }
                    float A0 = d0.x + d0.y, A1 = d1.x + d1.y, A2 = d2.x + d2.y;
                    float r = fsig(xr + A0);
                    float z = fsig(xz + A1);
                    float n = ftanh(xn + r * A2);
                    float hnew = n + z * (hold0 - n);
                    hold0 = hnew;
                    // broadcast h0(t) via readlane (VALU-only)
                    {
                        int hni = __float_as_int(hnew);
                        #pragma unroll
                        for (int k = 0; k < 16; k++) {
                            float e0 = __int_as_float(__builtin_amdgcn_readlane(hni, 2 * k));
                            float e1 = __int_as_float(__builtin_amdgcn_readlane(hni, 2 * k + 1));
                            h0v[k] = mkv2(e0, e1);
                        }
                    }
                    // xg1(t) k-half partials -> ring
                    v2f p0 = splat2(0.f), p1 = splat2(0.f), p2 = splat2(0.f);
                    #pragma unroll
                    for (int k = 0; k < 8; k++) {
                        v2f hh = h0v[8 * hlf + k];
                        p0 = v2fma(u1r[k], hh, p0);
                        p1 = v2fma(u1z[k], hh, p1);
                        p2 = v2fma(u1n[k], hh, p2);
                    }
                    float* wp = w1 + i * 192 + hlf * 96;
                    wp[j]      = p0.x + p0.y;
                    wp[j + 32] = p1.x + p1.y;
                    wp[j + 64] = p2.x + p2.y;
                }
            }
            __syncthreads();
        }
        // wave0 done (head is handled by wave1)
    } else {
        // =================== wave1: layer-1 + batch duty ===================
        // stage CT (wave1-private consumer, so stage it alone: no race)
        for (int idx = lane; idx < NF * G3; idx += 64)
            CT[idx] = Cg[(size_t)e * NF * G3 + idx];

        v2f w1r[16], w1z[16], w1n[16];          // Whh1 rows, full k
        {
            const float* base = Whh1 + (size_t)eG * NH;
            const float* r0 = base + (size_t)j * NH;
            const float* r1 = base + (size_t)(j + 32) * NH;
            const float* r2 = base + (size_t)(j + 64) * NH;
            #pragma unroll
            for (int q4 = 0; q4 < 8; q4++) {
                float4 qa = ((const float4*)r0)[q4];
                w1r[2*q4] = mkv2(qa.x, qa.y); w1r[2*q4+1] = mkv2(qa.z, qa.w);
                float4 qb = ((const float4*)r1)[q4];
                w1z[2*q4] = mkv2(qb.x, qb.y); w1z[2*q4+1] = mkv2(qb.z, qb.w);
                float4 qc = ((const float4*)r2)[q4];
                w1n[2*q4] = mkv2(qc.x, qc.y); w1n[2*q4+1] = mkv2(qc.z, qc.w);
            }
        }
        const float b1r = bhh1[eG + j];
        const float b1z = bhh1[eG + j + 32];
        const float b1n = bhh1[eG + j + 64];
        const float c1r = bih1[eG + j];
        const float c1z = bih1[eG + j + 32];
        const float c1n = bih1[eG + j + 64];

        // dreg = bih0 + Wih0 @ (b_in + h_embed)   (rows j, j+32, j+64)
        float dreg0, dreg1, dreg2;
        {
            float s0 = bih0[eG + j], s1 = bih0[eG + j + 32], s2 = bih0[eG + j + 64];
            const float* w0 = Wih0 + ((size_t)eG + j) * ND;
            const float* w1w = Wih0 + ((size_t)eG + j + 32) * ND;
            const float* w2 = Wih0 + ((size_t)eG + j + 64) * ND;
            for (int d = 0; d < ND; d++) {
                float bb = b_in[d] + emb[(size_t)hor * ND + d];
                s0 += w0[d] * bb; s1 += w1w[d] * bb; s2 += w2[d] * bb;
            }
            dreg0 = hlf ? 0.f : s0;
            dreg1 = hlf ? 0.f : s1;
            dreg2 = hlf ? 0.f : s2;
        }

        v2f h1v[16];
        #pragma unroll
        for (int k = 0; k < 16; k++) h1v[k] = splat2(0.f);
        float hold1 = 0.f;
        const float* xg = x + (size_t)b * LSEQ * NF;

        // ---- xg0 prep for target phase tp (stages x chunk when needed) ----
        auto xg0_prep = [&](int tp) {
            const int base = tp * TBLK;
            if (base % CHUNK == 0) {
                const float4* xc4 = (const float4*)(xg + (size_t)base * NF);
                for (int i4 = lane; i4 < (CHUNK * NF) / 4; i4 += 64) {
                    float4 v = xc4[i4];
                    int idx = i4 * 4;
                    #pragma unroll
                    for (int u = 0; u < 4; u++) {
                        int id = idx + u;
                        int it = (int)(((unsigned)id * 5243u) >> 18);   // id/50
                        int f  = id - it * 50;
                        float val = (u == 0) ? v.x : (u == 1) ? v.y : (u == 2) ? v.z : v.w;
                        xs[f * CHUNK + it] = val;
                    }
                }
            }
            const int off = base % CHUNK;
            v2f a0[4], a1[4], a2[4];
            #pragma unroll
            for (int pq = 0; pq < 4; pq++) {
                a0[pq] = splat2(dreg0); a1[pq] = splat2(dreg1); a2[pq] = splat2(dreg2);
            }
            const int fb = 25 * hlf;
            #pragma unroll 5
            for (int f = 0; f < 25; f++) {
                const int fg = fb + f;
                float cc0 = CT[fg * G3 + j];
                float cc1 = CT[fg * G3 + j + 32];
                float cc2 = CT[fg * G3 + j + 64];
                const float4* xp = (const float4*)(xs + fg * CHUNK + off);
                float4 xa = xp[0], xb = xp[1];
                v2f xv[4] = { mkv2(xa.x, xa.y), mkv2(xa.z, xa.w),
                              mkv2(xb.x, xb.y), mkv2(xb.z, xb.w) };
                v2f ww0 = splat2(cc0), ww1 = splat2(cc1), ww2 = splat2(cc2);
                #pragma unroll
                for (int pq = 0; pq < 4; pq++) {
                    a0[pq] = v2fma(ww0, xv[pq], a0[pq]);
                    a1[pq] = v2fma(ww1, xv[pq], a1[pq]);
                    a2[pq] = v2fma(ww2, xv[pq], a2[pq]);
                }
            }
            #pragma unroll
            for (int pq = 0; pq < 4; pq++) {
                a0[pq].x += __shfl_xor(a0[pq].x, 32, 64); a0[pq].y += __shfl_xor(a0[pq].y, 32, 64);
                a1[pq].x += __shfl_xor(a1[pq].x, 32, 64); a1[pq].y += __shfl_xor(a1[pq].y, 32, 64);
                a2[pq].x += __shfl_xor(a2[pq].x, 32, 64); a2[pq].y += __shfl_xor(a2[pq].y, 32, 64);
            }
            if (!hlf) {
                float* wp = rg0 + (tp & 1) * (TBLK * 96);
                #pragma unroll
                for (int pq = 0; pq < 4; pq++) {
                    #pragma unroll
                    for (int u = 0; u < 2; u++) {
                        int i = 2 * pq + u;
                        wp[i * 96 + j]      = a0[pq][u];
                        wp[i * 96 + 32 + j] = a1[pq][u];
                        wp[i * 96 + 64 + j] = a2[pq][u];
                    }
                }
            }
        };

        xg0_prep(0);          // prologue: xg0 for phase 0 (stages chunk 0)
        __syncthreads();

        for (int p = 0; p < NPHASE; p++) {
            if (p >= 1) {
                const float* r1 = rg1 + ((p - 1) & 1) * (TBLK * 192);
                #pragma unroll
                for (int i = 0; i < TBLK; i++) {
                    const float* rp = r1 + i * 192;
                    float xr = rp[j]      + rp[96 + j]      + c1r;
                    float xz = rp[32 + j] + rp[96 + 32 + j] + c1z;
                    float xn = rp[64 + j] + rp[96 + 64 + j] + c1n;
                    v2f g0 = mkv2(b1r, 0.f), g1 = mkv2(b1z, 0.f), g2 = mkv2(b1n, 0.f);
                    #pragma unroll
                    for (int k = 0; k < 16; k++) {
                        g0 = v2fma(w1r[k], h1v[k], g0);
                        g1 = v2fma(w1z[k], h1v[k], g1);
                        g2 = v2fma(w1n[k], h1v[k], g2);
                    }
                    float G0 = g0.x + g0.y, G1 = g1.x + g1.y, G2 = g2.x + g2.y;
                    float r1g = fsig(xr + G0);
                    float z1g = fsig(xz + G1);
                    float n1g = ftanh(xn + r1g * G2);
                    float hnew = n1g + z1g * (hold1 - n1g);
                    hold1 = hnew;
                    {
                        int hni = __float_as_int(hnew);
                        #pragma unroll
                        for (int k = 0; k < 16; k++) {
                            float e0 = __int_as_float(__builtin_amdgcn_readlane(hni, 2 * k));
                            float e1 = __int_as_float(__builtin_amdgcn_readlane(hni, 2 * k + 1));
                            h1v[k] = mkv2(e0, e1);
                        }
                    }
                }
            }
            if (p <= NCOMP - 2) xg0_prep(p + 1);
            __syncthreads();
        }

        // ---- head MLP (wave1 holds full h1 in h1v) ----
        {
            float s = bh1[e * NHU + j];
            const float* wr = Wh1 + ((size_t)e * NHU + j) * NH;
            #pragma unroll
            for (int k = 0; k < 16; k++) {
                v2f wv = mkv2(wr[2 * k], wr[2 * k + 1]);
                v2f pr = wv * h1v[k];
                s += pr.x + pr.y;
            }
            float hid = fmaxf(s, 0.f);
            float c = hid * Wh2[e * NHU + j];
            #pragma unroll
            for (int off = 16; off > 0; off >>= 1) c += __shfl_down(c, off, 64);
            if (lane == 0) atomicAdd(out + b, wgt * (c + bh2[e]));
        }
    }
}

extern "C" void kernel_launch(void* const* d_in, const int* in_sizes, int n_in,
                              void* d_out, int out_size, void* d_ws, size_t ws_size,
                              hipStream_t stream) {
    const float* x       = (const float*)d_in[0];
    const int*   horizon = (const int*)  d_in[1];
    const float* W_in    = (const float*)d_in[2];
    const float* b_in    = (const float*)d_in[3];
    const float* emb     = (const float*)d_in[4];
    const float* W_gate  = (const float*)d_in[5];
    const float* b_gate  = (const float*)d_in[6];
    const float* Wih0    = (const float*)d_in[7];
    const float* Whh0    = (const float*)d_in[8];
    const float* bih0    = (const float*)d_in[9];
    const float* bhh0    = (const float*)d_in[10];
    const float* Wih1    = (const float*)d_in[11];
    const float* Whh1    = (const float*)d_in[12];
    const float* bih1    = (const float*)d_in[13];
    const float* bhh1    = (const float*)d_in[14];
    const float* Wh1     = (const float*)d_in[15];
    const float* bh1     = (const float*)d_in[16];
    const float* Wh2     = (const float*)d_in[17];
    const float* bh2     = (const float*)d_in[18];
    float* out = (float*)d_out;
    float* Cg  = (float*)d_ws;   // NE*NF*G3 floats = 76.8 KB

    hipMemsetAsync(d_out, 0, NB * sizeof(float), stream);
    compute_C_kernel<<<dim3(NE), dim3(256), 0, stream>>>(Wih0, W_in, Cg);
    moe_gru_kernel<<<dim3(NB * NE), dim3(128), 0, stream>>>(
        x, horizon, emb, W_gate, b_gate, b_in,
        Wih0, Whh0, bih0, bhh0, Wih1, Whh1, bih1, bhh1,
        Wh1, bh1, Wh2, bh2, Cg, out);
}